// Round 1
// baseline (1115.028 us; speedup 1.0000x reference)
//
#include <hip/hip_runtime.h>

#define NB 8
#define NC 512
#define NL 8192
#define NH 8
#define ND 64

typedef float f32x4 __attribute__((ext_vector_type(4)));
typedef __bf16 bf16x8 __attribute__((ext_vector_type(8)));
typedef unsigned int u32x4 __attribute__((ext_vector_type(4)));

__device__ __forceinline__ unsigned short f2bf(float f) {
    unsigned u = __builtin_bit_cast(unsigned, f);
    u += 0x7fffu + ((u >> 16) & 1u);
    return (unsigned short)(u >> 16);
}
__device__ __forceinline__ float bf2f(unsigned short s) {
    unsigned u = ((unsigned)s) << 16;
    return __builtin_bit_cast(float, u);
}
__device__ __forceinline__ bf16x8 frag_from_u32x4(u32x4 v) {
    return __builtin_bit_cast(bf16x8, v);
}
// LDS fragment load: only 4B alignment guaranteed (row stride 68B) -> dword reads
__device__ __forceinline__ bf16x8 ld_frag_lds(const unsigned short* p) {
    const unsigned* q = (const unsigned*)p;
    u32x4 v = { q[0], q[1], q[2], q[3] };
    return frag_from_u32x4(v);
}
// Global fragment load: 16B aligned
__device__ __forceinline__ bf16x8 ld_frag_g16(const unsigned short* p) {
    return frag_from_u32x4(*(const u32x4*)p);
}

__global__ __launch_bounds__(256) void cvt_w_kernel(const float* __restrict__ s,
                                                    unsigned short* __restrict__ d, int n) {
    int i = blockIdx.x * 256 + threadIdx.x;
    if (i < n) d[i] = f2bf(s[i]);
}

__global__ __launch_bounds__(256) void zero_kernel(float* __restrict__ p, int n) {
    int i = blockIdx.x * 256 + threadIdx.x;
    if (i < n) p[i] = 0.f;
}

// Y[b,o,l] = sum_c W[o,c] X[b,c,l] + bias[o]  (+ resid)
// grid: (256 = 64 ntile * 4 mtile, NB); block 256
template<bool XBF, bool RESID>
__global__ __launch_bounds__(256) void gemm_kernel(
    const unsigned short* __restrict__ Wb,   // [512,512] bf16, row-major (o,c)
    const void* __restrict__ Xv,             // [B,512,L] float or bf16(ushort)
    const float* __restrict__ bias,          // [512]
    const float* __restrict__ resid,         // [B,512,L] float (RESID only)
    void* __restrict__ Yv)                   // bf16 or float
{
    const int nt = blockIdx.x >> 2;   // 0..63  (mt fastest -> X-tile L2 reuse)
    const int mt = blockIdx.x & 3;    // 0..3
    const int b  = blockIdx.y;
    const int t  = threadIdx.x;
    const int wave = t >> 6, lane = t & 63;
    const int m0 = mt * 128, n0 = nt * 128;
    const int wm = (wave & 1) * 64, wn = (wave >> 1) * 64;

    __shared__ alignas(16) unsigned short lA[128][34]; // [m][k], stride 34 (17 dwords, odd)
    __shared__ alignas(16) unsigned short lX[128][34]; // [n=l][k=c] transposed

    f32x4 acc[4][4] = {};

    const float* Xf = (const float*)Xv;
    const unsigned short* Xh = (const unsigned short*)Xv;
    const size_t xbase = (size_t)b * NC * NL;

    for (int k0 = 0; k0 < NC; k0 += 32) {
        // stage A (bf16 weights), 128x32
        {
            int id = t;
            #pragma unroll
            for (int it = 0; it < 2; ++it, id += 256) {
                const int r = id >> 2, s = id & 3;
                u32x4 v = *(const u32x4*)(Wb + (m0 + r) * NC + k0 + s * 8);
                unsigned* p = (unsigned*)&lA[r][s * 8];
                p[0] = v.x; p[1] = v.y; p[2] = v.z; p[3] = v.w;
            }
        }
        // stage X transposed into [l][c]
        if constexpr (!XBF) {
            #pragma unroll
            for (int it = 0; it < 16; ++it) {
                const int kr = it * 2 + (t >> 7);
                const int l  = t & 127;
                lX[l][kr] = f2bf(Xf[xbase + (size_t)(k0 + kr) * NL + n0 + l]);
            }
        } else {
            #pragma unroll
            for (int it = 0; it < 8; ++it) {
                const int kr = it * 4 + (t >> 6);
                const int l2 = (t & 63) * 2;
                unsigned v = *(const unsigned*)(Xh + xbase + (size_t)(k0 + kr) * NL + n0 + l2);
                lX[l2][kr]     = (unsigned short)(v & 0xffffu);
                lX[l2 + 1][kr] = (unsigned short)(v >> 16);
            }
        }
        __syncthreads();

        const int koff = (lane >> 4) * 8;
        bf16x8 af[4], bfx[4];
        #pragma unroll
        for (int i = 0; i < 4; ++i)
            af[i] = ld_frag_lds(&lA[wm + i * 16 + (lane & 15)][koff]);
        #pragma unroll
        for (int j = 0; j < 4; ++j)
            bfx[j] = ld_frag_lds(&lX[wn + j * 16 + (lane & 15)][koff]);
        #pragma unroll
        for (int i = 0; i < 4; ++i)
            #pragma unroll
            for (int j = 0; j < 4; ++j)
                acc[i][j] = __builtin_amdgcn_mfma_f32_16x16x32_bf16(af[i], bfx[j], acc[i][j], 0, 0, 0);
        __syncthreads();
    }

    // epilogue: C/D layout col=lane&15, row=(lane>>4)*4+reg
    const int col = lane & 15, row0 = (lane >> 4) * 4;
    #pragma unroll
    for (int i = 0; i < 4; ++i) {
        #pragma unroll
        for (int r = 0; r < 4; ++r) {
            const int o = m0 + wm + i * 16 + row0 + r;
            const float bo = bias[o];
            const size_t rb = (size_t)b * NC * NL + (size_t)o * NL + n0 + wn;
            if constexpr (RESID) {
                float* Y = (float*)Yv;
                #pragma unroll
                for (int j = 0; j < 4; ++j) {
                    const size_t idx = rb + j * 16 + col;
                    Y[idx] = acc[i][j][r] + bo + resid[idx];
                }
            } else {
                unsigned short* Y = (unsigned short*)Yv;
                #pragma unroll
                for (int j = 0; j < 4; ++j)
                    Y[rb + j * 16 + col] = f2bf(acc[i][j][r] + bo);
            }
        }
    }
}

// in-place softmax over rows of 8192 (bf16), one block per row
__global__ __launch_bounds__(256) void softmax_rows(unsigned short* __restrict__ P) {
    const int row = blockIdx.x;
    const int t = threadIdx.x;
    const int wave = t >> 6, lane = t & 63;
    unsigned short* p = P + (size_t)row * NL;

    float v[32];
    float mx = -1e30f;
    #pragma unroll
    for (int i = 0; i < 4; ++i) {
        u32x4 raw = *(const u32x4*)(p + (size_t)(i * 256 + t) * 8);
        #pragma unroll
        for (int d = 0; d < 4; ++d) {
            unsigned w = raw[d];
            v[i * 8 + d * 2]     = bf2f((unsigned short)(w & 0xffffu));
            v[i * 8 + d * 2 + 1] = bf2f((unsigned short)(w >> 16));
        }
        #pragma unroll
        for (int j = 0; j < 8; ++j) mx = fmaxf(mx, v[i * 8 + j]);
    }
    #pragma unroll
    for (int off = 32; off > 0; off >>= 1) mx = fmaxf(mx, __shfl_down(mx, off));
    __shared__ float red[16];
    if (lane == 0) red[wave] = mx;
    __syncthreads();
    mx = fmaxf(fmaxf(red[0], red[1]), fmaxf(red[2], red[3]));

    float s = 0.f;
    #pragma unroll
    for (int i = 0; i < 32; ++i) { v[i] = __expf(v[i] - mx); s += v[i]; }
    #pragma unroll
    for (int off = 32; off > 0; off >>= 1) s += __shfl_down(s, off);
    if (lane == 0) red[8 + wave] = s;
    __syncthreads();
    s = red[8] + red[9] + red[10] + red[11];
    const float inv = 1.0f / s;

    #pragma unroll
    for (int i = 0; i < 4; ++i) {
        u32x4 outw;
        #pragma unroll
        for (int d = 0; d < 4; ++d) {
            unsigned lo = f2bf(v[i * 8 + d * 2] * inv);
            unsigned hi = f2bf(v[i * 8 + d * 2 + 1] * inv);
            outw[d] = lo | (hi << 16);
        }
        *(u32x4*)(p + (size_t)(i * 256 + t) * 8) = outw;
    }
}

// ctx[bh,i,j] = sum_l Ksm[bh,i,l] * V[bh,j,l]   grid (64, 16 L-splits), atomicAdd
__global__ __launch_bounds__(256) void ctx_kernel(
    const unsigned short* __restrict__ K,
    const unsigned short* __restrict__ V,
    float* __restrict__ ctx)
{
    const int bh = blockIdx.x;
    const int sp = blockIdx.y;
    const int t = threadIdx.x;
    const int wave = t >> 6, lane = t & 63;
    const size_t base = (size_t)bh * ND * NL;
    const int i = wave * 16 + (lane & 15);
    const int koff = (lane >> 4) * 8;
    const unsigned short* Ka = K + base + (size_t)i * NL + koff;

    f32x4 acc[4] = {};
    const int l0 = sp * (NL / 16);
    for (int l = l0; l < l0 + (NL / 16); l += 32) {
        bf16x8 a = ld_frag_g16(Ka + l);
        #pragma unroll
        for (int j = 0; j < 4; ++j) {
            bf16x8 bv = ld_frag_g16(V + base + (size_t)(j * 16 + (lane & 15)) * NL + l + koff);
            acc[j] = __builtin_amdgcn_mfma_f32_16x16x32_bf16(a, bv, acc[j], 0, 0, 0);
        }
    }
    const int col = lane & 15, row0 = (lane >> 4) * 4;
    #pragma unroll
    for (int j = 0; j < 4; ++j)
        #pragma unroll
        for (int r = 0; r < 4; ++r)
            atomicAdd(&ctx[(size_t)bh * (ND * ND) + (size_t)(wave * 16 + row0 + r) * ND + j * 16 + col],
                      acc[j][r]);
}

// att[bh,v,l] = sum_k ctx[bh,k,v] * softmax_k(Qp[bh,k,l]); grid (NL/256, 64)
__global__ __launch_bounds__(256) void att_kernel(
    const unsigned short* __restrict__ Qp,
    const float* __restrict__ ctx,
    unsigned short* __restrict__ att)
{
    const int bh = blockIdx.y;
    const int l = blockIdx.x * 256 + threadIdx.x;
    const int t = threadIdx.x;

    __shared__ float lctx[64][64];
    for (int i = t; i < ND * ND; i += 256)
        lctx[i >> 6][i & 63] = ctx[(size_t)bh * ND * ND + i];
    __syncthreads();

    const size_t base = (size_t)bh * ND * NL;
    float q[64];
    float mx = -1e30f;
    #pragma unroll
    for (int k = 0; k < 64; ++k) {
        q[k] = bf2f(Qp[base + (size_t)k * NL + l]);
        mx = fmaxf(mx, q[k]);
    }
    float s = 0.f;
    #pragma unroll
    for (int k = 0; k < 64; ++k) { q[k] = __expf(q[k] - mx); s += q[k]; }
    const float inv = 1.0f / s;
    #pragma unroll
    for (int k = 0; k < 64; ++k) q[k] *= inv;

    for (int vg = 0; vg < 16; ++vg) {
        f32x4 a = {};
        #pragma unroll
        for (int k = 0; k < 64; ++k) {
            f32x4 c = *(const f32x4*)&lctx[k][vg * 4];
            a += q[k] * c;
        }
        #pragma unroll
        for (int u = 0; u < 4; ++u)
            att[base + (size_t)(vg * 4 + u) * NL + l] = f2bf(a[u]);
    }
}

extern "C" void kernel_launch(void* const* d_in, const int* in_sizes, int n_in,
                              void* d_out, int out_size, void* d_ws, size_t ws_size,
                              hipStream_t stream) {
    (void)in_sizes; (void)n_in; (void)out_size; (void)ws_size;
    const float* input_   = (const float*)d_in[0];
    const float* context_ = (const float*)d_in[1];
    const float* Wk = (const float*)d_in[2];
    const float* bk = (const float*)d_in[3];
    const float* Wq = (const float*)d_in[4];
    const float* bq = (const float*)d_in[5];
    const float* Wv = (const float*)d_in[6];
    const float* bv = (const float*)d_in[7];
    const float* Wr = (const float*)d_in[8];
    const float* br = (const float*)d_in[9];
    float* out = (float*)d_out;

    // workspace layout (~204 MB):
    char* ws = (char*)d_ws;
    unsigned short* Wkb = (unsigned short*)ws;            // 4 x 512x512 bf16 = 2 MB
    unsigned short* Wqb = Wkb + NC * NC;
    unsigned short* Wvb = Wqb + NC * NC;
    unsigned short* Wrb = Wvb + NC * NC;
    float* ctxb = (float*)(ws + (size_t)4 * NC * NC * 2); // 64*64*64 f32 = 1 MB
    unsigned short* Kp = (unsigned short*)(ws + (size_t)4 * NC * NC * 2 + (size_t)NB * NH * ND * ND * 4);
    unsigned short* Qp = Kp + (size_t)NB * NC * NL;       // 67 MB each
    unsigned short* Vp = Qp + (size_t)NB * NC * NL;
    unsigned short* att = Kp;                             // reuse Kp after ctx

    const int wN = NC * NC;
    cvt_w_kernel<<<wN / 256, 256, 0, stream>>>(Wk, Wkb, wN);
    cvt_w_kernel<<<wN / 256, 256, 0, stream>>>(Wq, Wqb, wN);
    cvt_w_kernel<<<wN / 256, 256, 0, stream>>>(Wv, Wvb, wN);
    cvt_w_kernel<<<wN / 256, 256, 0, stream>>>(Wr, Wrb, wN);
    zero_kernel<<<(NB * NH * ND * ND) / 256, 256, 0, stream>>>(ctxb, NB * NH * ND * ND);

    dim3 gg(256, NB);
    gemm_kernel<false, false><<<gg, 256, 0, stream>>>(Wkb, context_, bk, nullptr, Kp);
    gemm_kernel<false, false><<<gg, 256, 0, stream>>>(Wqb, input_,  bq, nullptr, Qp);
    gemm_kernel<false, false><<<gg, 256, 0, stream>>>(Wvb, context_, bv, nullptr, Vp);

    softmax_rows<<<NB * NC, 256, 0, stream>>>(Kp);
    ctx_kernel<<<dim3(NB * NH, 16), 256, 0, stream>>>(Kp, Vp, ctxb);
    att_kernel<<<dim3(NL / 256, NB * NH), 256, 0, stream>>>(Qp, ctxb, att);

    gemm_kernel<true, true><<<gg, 256, 0, stream>>>(Wrb, att, br, input_, out);
}

// Round 2
// 857.777 us; speedup vs baseline: 1.2999x; 1.2999x over previous
//
#include <hip/hip_runtime.h>

#define NB 8
#define NC 512
#define NL 8192
#define NH 8
#define ND 64

typedef float f32x4 __attribute__((ext_vector_type(4)));
typedef __bf16 bf16x8 __attribute__((ext_vector_type(8)));
typedef unsigned int u32x4 __attribute__((ext_vector_type(4)));

__device__ __forceinline__ unsigned short f2bf(float f) {
    unsigned u = __builtin_bit_cast(unsigned, f);
    u += 0x7fffu + ((u >> 16) & 1u);
    return (unsigned short)(u >> 16);
}
__device__ __forceinline__ float bf2f(unsigned short s) {
    unsigned u = ((unsigned)s) << 16;
    return __builtin_bit_cast(float, u);
}
__device__ __forceinline__ float bf2f_lo(unsigned w) {
    return __builtin_bit_cast(float, w << 16);
}
__device__ __forceinline__ float bf2f_hi(unsigned w) {
    return __builtin_bit_cast(float, w & 0xffff0000u);
}
__device__ __forceinline__ bf16x8 frag_from_u32x4(u32x4 v) {
    return __builtin_bit_cast(bf16x8, v);
}
// LDS fragment load with only-4B-aligned rows -> dword reads
__device__ __forceinline__ bf16x8 ld_frag_lds(const unsigned short* p) {
    const unsigned* q = (const unsigned*)p;
    u32x4 v = { q[0], q[1], q[2], q[3] };
    return frag_from_u32x4(v);
}
// Global fragment load: 16B aligned
__device__ __forceinline__ bf16x8 ld_frag_g16(const unsigned short* p) {
    return frag_from_u32x4(*(const u32x4*)p);
}

__global__ __launch_bounds__(256) void cvt_w_kernel(const float* __restrict__ s,
                                                    unsigned short* __restrict__ d, int n) {
    int i = blockIdx.x * 256 + threadIdx.x;
    if (i < n) d[i] = f2bf(s[i]);
}

__global__ __launch_bounds__(256) void zero_kernel(float* __restrict__ p, int n) {
    int i = blockIdx.x * 256 + threadIdx.x;
    if (i < n) p[i] = 0.f;
}

// bkv = [bk ; bv]
__global__ __launch_bounds__(256) void concat_bias_kernel(const float* __restrict__ a,
                                                          const float* __restrict__ b,
                                                          float* __restrict__ d) {
    int i = blockIdx.x * 256 + threadIdx.x;
    d[i] = (i < NC) ? a[i] : b[i - NC];
}

// Y[b,o,l] = sum_c W[o,c] X[b,c,l] + bias[o]  (+ resid)
// MT = number of 128-row m-tiles (OC = MT*128). grid: (64*MT, NB), block 256.
template<int MT, bool XBF, bool RESID, bool PERB>
__global__ __launch_bounds__(256) void gemm_kernel(
    const unsigned short* __restrict__ Wb,   // [OC,512] bf16 (PERB: per-batch [B][512][512])
    const void* __restrict__ Xv,             // [B,512,L] float or bf16(ushort)
    const float* __restrict__ bias,          // [OC]
    const float* __restrict__ resid,         // [B,512,L] float (RESID only)
    void* __restrict__ Yv)                   // bf16 (ushort) or float
{
    const int nt = blockIdx.x / MT;          // 0..63 (mt fastest -> X-tile L2 reuse)
    const int mt = blockIdx.x % MT;
    const int b  = blockIdx.y;
    const int t  = threadIdx.x;
    const int wave = t >> 6, lane = t & 63;
    const int m0 = mt * 128, n0 = nt * 128;
    const int wm = (wave & 1) * 64, wn = (wave >> 1) * 64;
    const int OC = MT * 128;

    __shared__ alignas(16) unsigned short lA[128][34]; // [m][k], stride 34 (17 dwords, odd)
    __shared__ alignas(16) unsigned short lX[128][34]; // [n=l][k=c] transposed

    f32x4 acc[4][4] = {};

    const float* Xf = (const float*)Xv;
    const unsigned short* Xh = (const unsigned short*)Xv;
    const size_t xbase = (size_t)b * NC * NL;
    const unsigned short* Wp = Wb + (PERB ? (size_t)b * NC * NC : 0);

    for (int k0 = 0; k0 < NC; k0 += 32) {
        // stage W (bf16), 128x32
        {
            int id = t;
            #pragma unroll
            for (int it = 0; it < 2; ++it, id += 256) {
                const int r = id >> 2, s = id & 3;
                u32x4 v = *(const u32x4*)(Wp + (size_t)(m0 + r) * NC + k0 + s * 8);
                unsigned* p = (unsigned*)&lA[r][s * 8];
                p[0] = v.x; p[1] = v.y; p[2] = v.z; p[3] = v.w;
            }
        }
        // stage X transposed into [l][c]
        if constexpr (!XBF) {
            #pragma unroll
            for (int it = 0; it < 16; ++it) {
                const int kr = it * 2 + (t >> 7);
                const int l  = t & 127;
                lX[l][kr] = f2bf(Xf[xbase + (size_t)(k0 + kr) * NL + n0 + l]);
            }
        } else {
            #pragma unroll
            for (int it = 0; it < 8; ++it) {
                const int kr = it * 4 + (t >> 6);
                const int l2 = (t & 63) * 2;
                unsigned v = *(const unsigned*)(Xh + xbase + (size_t)(k0 + kr) * NL + n0 + l2);
                lX[l2][kr]     = (unsigned short)(v & 0xffffu);
                lX[l2 + 1][kr] = (unsigned short)(v >> 16);
            }
        }
        __syncthreads();

        const int koff = (lane >> 4) * 8;
        bf16x8 af[4], bfx[4];
        #pragma unroll
        for (int i = 0; i < 4; ++i)
            af[i] = ld_frag_lds(&lA[wm + i * 16 + (lane & 15)][koff]);
        #pragma unroll
        for (int j = 0; j < 4; ++j)
            bfx[j] = ld_frag_lds(&lX[wn + j * 16 + (lane & 15)][koff]);
        #pragma unroll
        for (int i = 0; i < 4; ++i)
            #pragma unroll
            for (int j = 0; j < 4; ++j)
                acc[i][j] = __builtin_amdgcn_mfma_f32_16x16x32_bf16(af[i], bfx[j], acc[i][j], 0, 0, 0);
        __syncthreads();
    }

    // epilogue: C/D layout col=lane&15, row=(lane>>4)*4+reg
    const int col = lane & 15, row0 = (lane >> 4) * 4;
    #pragma unroll
    for (int i = 0; i < 4; ++i) {
        #pragma unroll
        for (int r = 0; r < 4; ++r) {
            const int o = m0 + wm + i * 16 + row0 + r;
            const float bo = bias[o];
            const size_t rb = (size_t)b * OC * NL + (size_t)o * NL + n0 + wn;
            if constexpr (RESID) {
                float* Y = (float*)Yv;
                #pragma unroll
                for (int j = 0; j < 4; ++j) {
                    const size_t idx = rb + j * 16 + col;
                    Y[idx] = acc[i][j][r] + bo + resid[idx];
                }
            } else {
                unsigned short* Y = (unsigned short*)Yv;
                #pragma unroll
                for (int j = 0; j < 4; ++j)
                    Y[rb + j * 16 + col] = f2bf(acc[i][j][r] + bo);
            }
        }
    }
}

// in-place softmax over rows of 8192 (bf16), one block per row (K channels of KVp)
__global__ __launch_bounds__(256) void softmax_rows(unsigned short* __restrict__ KV) {
    const int row = blockIdx.x;             // 0..NB*NC-1
    const int t = threadIdx.x;
    const int wave = t >> 6, lane = t & 63;
    unsigned short* p = KV + ((size_t)(row >> 9) * 2 * NC + (row & 511)) * NL;

    float v[32];
    float mx = -1e30f;
    #pragma unroll
    for (int i = 0; i < 4; ++i) {
        u32x4 raw = *(const u32x4*)(p + (size_t)(i * 256 + t) * 8);
        #pragma unroll
        for (int d = 0; d < 4; ++d) {
            unsigned w = raw[d];
            v[i * 8 + d * 2]     = bf2f_lo(w);
            v[i * 8 + d * 2 + 1] = bf2f_hi(w);
        }
        #pragma unroll
        for (int j = 0; j < 8; ++j) mx = fmaxf(mx, v[i * 8 + j]);
    }
    #pragma unroll
    for (int off = 32; off > 0; off >>= 1) mx = fmaxf(mx, __shfl_down(mx, off));
    __shared__ float red[16];
    if (lane == 0) red[wave] = mx;
    __syncthreads();
    mx = fmaxf(fmaxf(red[0], red[1]), fmaxf(red[2], red[3]));

    float s = 0.f;
    #pragma unroll
    for (int i = 0; i < 32; ++i) { v[i] = __expf(v[i] - mx); s += v[i]; }
    #pragma unroll
    for (int off = 32; off > 0; off >>= 1) s += __shfl_down(s, off);
    if (lane == 0) red[8 + wave] = s;
    __syncthreads();
    s = red[8] + red[9] + red[10] + red[11];
    const float inv = 1.0f / s;

    #pragma unroll
    for (int i = 0; i < 4; ++i) {
        u32x4 outw;
        #pragma unroll
        for (int d = 0; d < 4; ++d) {
            unsigned lo = f2bf(v[i * 8 + d * 2] * inv);
            unsigned hi = f2bf(v[i * 8 + d * 2 + 1] * inv);
            outw[d] = lo | (hi << 16);
        }
        *(u32x4*)(p + (size_t)(i * 256 + t) * 8) = outw;
    }
}

// in-place softmax over the 64 head-channels of Qp; 2 l per thread.
// grid (NL/512, NB*NH), block 256
__global__ __launch_bounds__(256) void qsoftmax_kernel(unsigned short* __restrict__ Qp) {
    const int bh = blockIdx.y;
    const int l0 = blockIdx.x * 512 + threadIdx.x * 2;
    unsigned short* p = Qp + (size_t)bh * ND * NL + l0;

    unsigned d[64];
    float m0 = -1e30f, m1 = -1e30f;
    #pragma unroll
    for (int k = 0; k < 64; ++k) {
        d[k] = *(const unsigned*)(p + (size_t)k * NL);
        m0 = fmaxf(m0, bf2f_lo(d[k]));
        m1 = fmaxf(m1, bf2f_hi(d[k]));
    }
    float s0 = 0.f, s1 = 0.f;
    #pragma unroll
    for (int k = 0; k < 64; ++k) {
        float e0 = __expf(bf2f_lo(d[k]) - m0);
        float e1 = __expf(bf2f_hi(d[k]) - m1);
        s0 += e0; s1 += e1;
        d[k] = (unsigned)f2bf(e0) | ((unsigned)f2bf(e1) << 16);
    }
    const float i0 = 1.0f / s0, i1 = 1.0f / s1;
    #pragma unroll
    for (int k = 0; k < 64; ++k) {
        unsigned lo = f2bf(bf2f_lo(d[k]) * i0);
        unsigned hi = f2bf(bf2f_hi(d[k]) * i1);
        *(unsigned*)(p + (size_t)k * NL) = lo | (hi << 16);
    }
}

// ctx[bh,k,v] = sum_l Ksm[b,h,k,l] * V[b,h,v,l]   grid (64, 16 L-splits), atomicAdd
__global__ __launch_bounds__(256) void ctx_kernel(
    const unsigned short* __restrict__ KV,   // [B][1024][L]: rows 0-511 K(softmaxed), 512-1023 V
    float* __restrict__ ctx)                 // [64][64][64]
{
    const int bh = blockIdx.x;
    const int sp = blockIdx.y;
    const int t = threadIdx.x;
    const int wave = t >> 6, lane = t & 63;
    const int b = bh >> 3, h = bh & 7;
    const size_t base_k = ((size_t)b * 2 * NC + h * ND) * NL;
    const size_t base_v = base_k + (size_t)NC * NL;
    const int i = wave * 16 + (lane & 15);
    const int koff = (lane >> 4) * 8;
    const unsigned short* Ka = KV + base_k + (size_t)i * NL + koff;

    f32x4 acc[4] = {};
    const int l0 = sp * (NL / 16);
    for (int l = l0; l < l0 + (NL / 16); l += 32) {
        bf16x8 a = ld_frag_g16(Ka + l);
        #pragma unroll
        for (int j = 0; j < 4; ++j) {
            bf16x8 bv = ld_frag_g16(KV + base_v + (size_t)(j * 16 + (lane & 15)) * NL + l + koff);
            acc[j] = __builtin_amdgcn_mfma_f32_16x16x32_bf16(a, bv, acc[j], 0, 0, 0);
        }
    }
    const int col = lane & 15, row0 = (lane >> 4) * 4;
    #pragma unroll
    for (int j = 0; j < 4; ++j)
        #pragma unroll
        for (int r = 0; r < 4; ++r)
            atomicAdd(&ctx[(size_t)bh * (ND * ND) + (size_t)(wave * 16 + row0 + r) * ND + j * 16 + col],
                      acc[j][r]);
}

// M_b[o, h*64+k] = sum_v Wr[o, h*64+v] * ctx[b,h,k,v]
// grid 64 blocks (bh), 512 threads = 8 waves; wave covers 64 o-rows
__global__ __launch_bounds__(512) void fold_kernel(
    const unsigned short* __restrict__ Wrb,  // [512][512] bf16
    const float* __restrict__ ctxb,          // [64][64][64]
    unsigned short* __restrict__ Mb)         // [B][512][512] bf16
{
    const int bh = blockIdx.x;
    const int b = bh >> 3, h = bh & 7;
    const int t = threadIdx.x;
    const int wave = t >> 6, lane = t & 63;

    __shared__ unsigned short lc[64 * 66];   // ctx bf16 [k][v], padded stride 66
    const float* cs = ctxb + (size_t)bh * (ND * ND);
    #pragma unroll
    for (int it = 0; it < 8; ++it) {
        int i = it * 512 + t;
        lc[(i >> 6) * 66 + (i & 63)] = f2bf(cs[i]);
    }
    __syncthreads();

    const int koff = (lane >> 4) * 8;
    f32x4 acc[4][4] = {};
    #pragma unroll
    for (int kk = 0; kk < 64; kk += 32) {
        bf16x8 af[4], bfx[4];
        #pragma unroll
        for (int i = 0; i < 4; ++i)
            af[i] = ld_frag_g16(Wrb + (size_t)(wave * 64 + i * 16 + (lane & 15)) * NC
                                + h * ND + kk + koff);
        #pragma unroll
        for (int j = 0; j < 4; ++j)
            bfx[j] = ld_frag_lds(&lc[(j * 16 + (lane & 15)) * 66 + kk + koff]);
        #pragma unroll
        for (int i = 0; i < 4; ++i)
            #pragma unroll
            for (int j = 0; j < 4; ++j)
                acc[i][j] = __builtin_amdgcn_mfma_f32_16x16x32_bf16(af[i], bfx[j], acc[i][j], 0, 0, 0);
    }

    const int col = lane & 15, row0 = (lane >> 4) * 4;
    #pragma unroll
    for (int i = 0; i < 4; ++i)
        #pragma unroll
        for (int r = 0; r < 4; ++r) {
            const int o = wave * 64 + i * 16 + row0 + r;
            #pragma unroll
            for (int j = 0; j < 4; ++j)
                Mb[(size_t)b * NC * NC + (size_t)o * NC + h * ND + j * 16 + col]
                    = f2bf(acc[i][j][r]);
        }
}

extern "C" void kernel_launch(void* const* d_in, const int* in_sizes, int n_in,
                              void* d_out, int out_size, void* d_ws, size_t ws_size,
                              hipStream_t stream) {
    (void)in_sizes; (void)n_in; (void)out_size; (void)ws_size;
    const float* input_   = (const float*)d_in[0];
    const float* context_ = (const float*)d_in[1];
    const float* Wk = (const float*)d_in[2];
    const float* bk = (const float*)d_in[3];
    const float* Wq = (const float*)d_in[4];
    const float* bq = (const float*)d_in[5];
    const float* Wv = (const float*)d_in[6];
    const float* bv = (const float*)d_in[7];
    const float* Wr = (const float*)d_in[8];
    const float* br = (const float*)d_in[9];
    float* out = (float*)d_out;

    // workspace layout (~204 MB):
    char* ws = (char*)d_ws;
    unsigned short* Wkvb = (unsigned short*)ws;                     // [1024][512] bf16 = 1 MB
    unsigned short* Wqb  = Wkvb + 2 * NC * NC;                      // 512 KB
    unsigned short* Wrb  = Wqb + NC * NC;                           // 512 KB
    float* bkv  = (float*)(Wrb + NC * NC);                          // 4 KB
    float* ctxb = bkv + 2 * NC;                                     // 1 MB
    unsigned short* KVp = (unsigned short*)(ctxb + NB * NH * ND * ND); // [B][1024][L] = 134 MB
    unsigned short* Qp  = KVp + (size_t)NB * 2 * NC * NL;           // 67 MB
    unsigned short* Mb  = KVp;                                      // reuse KVp after ctx/fold

    const int wN = NC * NC;
    cvt_w_kernel<<<wN / 256, 256, 0, stream>>>(Wk, Wkvb, wN);
    cvt_w_kernel<<<wN / 256, 256, 0, stream>>>(Wv, Wkvb + wN, wN);
    cvt_w_kernel<<<wN / 256, 256, 0, stream>>>(Wq, Wqb, wN);
    cvt_w_kernel<<<wN / 256, 256, 0, stream>>>(Wr, Wrb, wN);
    concat_bias_kernel<<<4, 256, 0, stream>>>(bk, bv, bkv);
    zero_kernel<<<(NB * NH * ND * ND) / 256, 256, 0, stream>>>(ctxb, NB * NH * ND * ND);

    // K+V fused projection: [Wk;Wv] (1024x512) @ context -> KVp
    gemm_kernel<8, false, false, false><<<dim3(64 * 8, NB), 256, 0, stream>>>(
        Wkvb, context_, bkv, nullptr, KVp);
    // Q projection
    gemm_kernel<4, false, false, false><<<dim3(64 * 4, NB), 256, 0, stream>>>(
        Wqb, input_, bq, nullptr, Qp);

    softmax_rows<<<NB * NC, 256, 0, stream>>>(KVp);
    ctx_kernel<<<dim3(NB * NH, 16), 256, 0, stream>>>(KVp, ctxb);
    fold_kernel<<<NB * NH, 512, 0, stream>>>(Wrb, ctxb, Mb);
    qsoftmax_kernel<<<dim3(NL / 512, NB * NH), 256, 0, stream>>>(Qp);

    // out = M_b @ qsoftmax(Qp) + br + input
    gemm_kernel<4, true, true, true><<<dim3(64 * 4, NB), 256, 0, stream>>>(
        Mb, Qp, br, input_, out);
}